// Round 8
// baseline (310.135 us; speedup 1.0000x reference)
//
#include <hip/hip_runtime.h>
#include <hip/hip_bf16.h>
#include <stdint.h>

#define B_SZ 16384
#define P_SZ 8
#define D_SZ 512
#define A_SZ 64
#define K1 576    // D + A
#define H_SZ 1024
#define NSEG 64
#define MB_MAX 72               // max 256-row m-blocks after per-policy padding
#define BPAD (B_SZ + P_SZ*256)  // 18432 padded sorted-row capacity
#define PREP_BLOCKS (BPAD * 72 / 256)   // 5184
#define TR1_BLOCKS (P_SZ * 9 * 16)      // 1152  (576/64 x 1024/64)
#define TR2_BLOCKS (P_SZ * 16 * 8)      // 1024  (1024/64 x 512/64)
#define G1_GRID (BPAD / 64 * (H_SZ / 64) / 4)   // 1152 blocks (4608 waves)
#define G2_GRID (BPAD / 64 * (D_SZ / 64) / 4)   // 576 blocks  (2304 waves)

typedef __bf16 bf16_t;
typedef __bf16 bf16x8 __attribute__((ext_vector_type(8)));
typedef float f32x4 __attribute__((ext_vector_type(4)));

// ---------------- sort prep ----------------

__global__ __launch_bounds__(256) void hist_block(const int* __restrict__ pol,
                                                  int* __restrict__ blockhist,
                                                  int* __restrict__ rowidx) {
    __shared__ int lc[P_SZ];
    int t = threadIdx.x;
    if (t < P_SZ) lc[t] = 0;
    __syncthreads();
    int gid = blockIdx.x * 256 + t;
    rowidx[gid] = -1;
    if (gid < BPAD - B_SZ) rowidx[B_SZ + gid] = -1;
    atomicAdd(&lc[pol[gid]], 1);
    __syncthreads();
    if (t < P_SZ) blockhist[blockIdx.x * P_SZ + t] = lc[t];
}

// parallel reduction (was: 64 serial dependent global reads on one thread)
__global__ __launch_bounds__(256) void prefix_kernel(const int* __restrict__ blockhist,
                                                     int* __restrict__ counts,
                                                     int* __restrict__ cursors,
                                                     int* __restrict__ blk_p) {
    __shared__ int csh[P_SZ];
    int t = threadIdx.x;
    int p = t >> 5, i = t & 31;          // 8 policies x 32 lanes
    int s = blockhist[i * P_SZ + p] + blockhist[(i + 32) * P_SZ + p];
#pragma unroll
    for (int m = 16; m >= 1; m >>= 1) s += __shfl_xor(s, m, 32);
    if (i == 0) csh[p] = s;
    __syncthreads();
    if (t == 0) {
        int run = 0;
        for (int pp = 0; pp < P_SZ; ++pp) {
            counts[pp] = csh[pp];
            cursors[pp] = run;
            run += ((csh[pp] + 255) >> 8) * 256;
        }
    }
    if (t < MB_MAX) {
        int run = 0, val = -1;
#pragma unroll
        for (int pp = 0; pp < P_SZ; ++pp) {
            int nb = (csh[pp] + 255) >> 8;
            if (t >= run && t < run + nb) val = pp;
            run += nb;
        }
        blk_p[t] = val;
    }
}

__global__ __launch_bounds__(256) void scatter_agg(const int* __restrict__ pol,
                                                   int* __restrict__ cursors,
                                                   int* __restrict__ rowidx) {
    __shared__ int lc[P_SZ], base_s[P_SZ];
    int t = threadIdx.x;
    if (t < P_SZ) lc[t] = 0;
    __syncthreads();
    int i = blockIdx.x * 256 + t;
    int p = pol[i];
    int lpos = atomicAdd(&lc[p], 1);
    __syncthreads();
    if (t < P_SZ) base_s[t] = atomicAdd(&cursors[t], lc[t]);
    __syncthreads();
    rowidx[base_s[p] + lpos] = i;
}

// ---------------- prep_all: fused x-gather/convert + weight transposes ----------------

__global__ __launch_bounds__(256) void prep_all(const float* __restrict__ latents,
                                                const float* __restrict__ actions,
                                                const int* __restrict__ rowidx,
                                                const float* __restrict__ W1,
                                                const float* __restrict__ W2,
                                                bf16_t* __restrict__ xs,
                                                bf16_t* __restrict__ w1t,
                                                bf16_t* __restrict__ w2t) {
    int bx = blockIdx.x;
    int tid = threadIdx.x;
    if (bx < PREP_BLOCKS) {
        int idx = bx * 256 + tid;
        int s = idx / 72;
        int col = (idx - s * 72) * 8;
        int g = rowidx[s];
        bf16x8 o;
        if (g < 0) {
            o = (bf16x8){0,0,0,0,0,0,0,0};
        } else {
            const float* src;
            if (col < D_SZ) src = latents + (size_t)g * D_SZ + col;
            else            src = actions + (size_t)g * A_SZ + (col - D_SZ);
            f32x4 v0 = *(const f32x4*)src;
            f32x4 v1 = *(const f32x4*)(src + 4);
            o[0] = (bf16_t)v0[0]; o[1] = (bf16_t)v0[1]; o[2] = (bf16_t)v0[2]; o[3] = (bf16_t)v0[3];
            o[4] = (bf16_t)v1[0]; o[5] = (bf16_t)v1[1]; o[6] = (bf16_t)v1[2]; o[7] = (bf16_t)v1[3];
        }
        *(bf16x8*)(xs + (size_t)s * K1 + col) = o;
        return;
    }
    int tz = bx - PREP_BLOCKS;
    const float* Wp; bf16_t* WTp; int K, N, k0, n0;
    if (tz < TR1_BLOCKS) {
        int p = tz / 144, rem = tz % 144;    // 9 k-tiles x 16 n-tiles
        k0 = (rem / 16) * 64; n0 = (rem % 16) * 64;
        K = K1; N = H_SZ;
        Wp = W1 + (size_t)p * K1 * H_SZ;
        WTp = w1t + (size_t)p * H_SZ * K1;
    } else {
        int u = tz - TR1_BLOCKS;
        int p = u / 128, rem = u % 128;      // 16 k-tiles x 8 n-tiles
        k0 = (rem / 8) * 64; n0 = (rem % 8) * 64;
        K = H_SZ; N = D_SZ;
        Wp = W2 + (size_t)p * H_SZ * D_SZ;
        WTp = w2t + (size_t)p * D_SZ * H_SZ;
    }
    __shared__ float ls[64][65];
#pragma unroll
    for (int e = 0; e < 4; ++e) {
        int idx = e * 256 + tid;
        int kk = idx >> 4, nn = (idx & 15) * 4;
        f32x4 v = *(const f32x4*)&Wp[(size_t)(k0 + kk) * N + n0 + nn];
        ls[kk][nn]     = v[0];
        ls[kk][nn + 1] = v[1];
        ls[kk][nn + 2] = v[2];
        ls[kk][nn + 3] = v[3];
    }
    __syncthreads();
#pragma unroll
    for (int e = 0; e < 2; ++e) {
        int idx = e * 256 + tid;
        int nn = idx >> 3, ks = (idx & 7) * 8;
        bf16x8 o;
#pragma unroll
        for (int q = 0; q < 8; ++q) o[q] = (bf16_t)ls[ks + q][nn];
        *(bf16x8*)&WTp[(size_t)(n0 + nn) * K + k0 + ks] = o;
    }
}

// ---------------- GEMMs: register-fragment, ZERO LDS, ZERO barriers ----------------
// Round-7 post-mortem: GEMM time (~35-45us) invariant across 5 configs spanning 2x
// staged bytes, 2x drain count, 1.5x HBM traffic, 2.25->9 blocks/CU. Only invariant
// mechanism: block-wide vmcnt(0)+s_barrier lockstep -- every iter, all 4 waves pay
// the tail latency of the block's slowest of ~2048 loads, and co-resident blocks
// stall in phase. Fix: load MFMA fragments DIRECTLY global->VGPR (16B contiguous,
// aligned; same lane->element mapping the LDS path produced). No LDS, no barrier:
// each wave waits only on its own loads (per-wave compiler-scheduled vmcnt), tails
// average across ~12 waves/CU, and register loads have clean deps so the compiler
// CAN pipeline them across MFMAs (the glds->LDS aliasing that defeated rounds 2/6
// does not exist here). 4 waves/block share one 64-row A panel via L1; XCD swizzle
// (wave-granular) keeps A/B panels L2-local.

__global__ __launch_bounds__(256, 2) void gemm1_kernel(
    const bf16_t* __restrict__ xs, const bf16_t* __restrict__ w1t,
    const float* __restrict__ b1, const int* __restrict__ blk_p,
    bf16_t* __restrict__ h) {

    const int b = blockIdx.x;
    const int wid = (b & 7) * (G1_GRID / 8) + (b >> 3);   // XCD-contiguous block id
    const int mb = wid >> 2;          // 64-row tile, 0..287 (n fastest within XCD)
    const int nblk = wid & 3;
    const int p = blk_p[mb >> 2];     // policy uniform per 256 rows
    if (p < 0) return;

    const int tid = threadIdx.x;
    const int wave = tid >> 6, lane = tid & 63;
    const int l16 = lane & 15, qd = lane >> 4;

    const int m0 = mb * 64;
    const int n0 = (nblk * 4 + wave) * 64;   // wave-private 64x64 tile

    // fragment base pointers: lane (l16,qd) reads 16B at [row][k + qd*8]
    const bf16_t* arow[4];
    const bf16_t* brow[4];
#pragma unroll
    for (int i = 0; i < 4; ++i)
        arow[i] = xs + (size_t)(m0 + i * 16 + l16) * K1 + qd * 8;
#pragma unroll
    for (int j = 0; j < 4; ++j)
        brow[j] = w1t + ((size_t)p * H_SZ + n0 + j * 16 + l16) * K1 + qd * 8;

    f32x4 acc[4][4];
#pragma unroll
    for (int i = 0; i < 4; ++i)
#pragma unroll
        for (int j = 0; j < 4; ++j)
            acc[i][j] = (f32x4){0.f, 0.f, 0.f, 0.f};

    for (int kt = 0; kt < K1; kt += 32) {
        bf16x8 af[4], bfv[4];
#pragma unroll
        for (int i = 0; i < 4; ++i) af[i] = *(const bf16x8*)(arow[i] + kt);
#pragma unroll
        for (int j = 0; j < 4; ++j) bfv[j] = *(const bf16x8*)(brow[j] + kt);
#pragma unroll
        for (int i = 0; i < 4; ++i)
#pragma unroll
            for (int j = 0; j < 4; ++j)
                acc[i][j] = __builtin_amdgcn_mfma_f32_16x16x32_bf16(af[i], bfv[j], acc[i][j], 0, 0, 0);
    }

    // epilogue: bias + relu -> h (padded sorted layout)
#pragma unroll
    for (int i = 0; i < 4; ++i) {
#pragma unroll
        for (int r = 0; r < 4; ++r) {
            int ml = i * 16 + qd * 4 + r;               // C/D: row = quad*4 + reg
            size_t row = (size_t)(m0 + ml);
#pragma unroll
            for (int j = 0; j < 4; ++j) {
                int n = n0 + j * 16 + l16;              // C/D: col = lane&15
                float v = acc[i][j][r] + b1[p * H_SZ + n];
                h[row * H_SZ + n] = (bf16_t)fmaxf(v, 0.f);
            }
        }
    }
}

__global__ __launch_bounds__(256, 2) void gemm2_kernel(
    const bf16_t* __restrict__ h, const bf16_t* __restrict__ w2t,
    const float* __restrict__ b2, const int* __restrict__ blk_p,
    const int* __restrict__ rowidx, float* __restrict__ out) {

    const int b = blockIdx.x;
    const int wid = (b & 7) * (G2_GRID / 8) + (b >> 3);   // XCD-contiguous block id
    const int mb = wid >> 1;          // 64-row tile, 0..287
    const int nblk = wid & 1;
    const int p = blk_p[mb >> 2];
    if (p < 0) return;

    const int tid = threadIdx.x;
    const int wave = tid >> 6, lane = tid & 63;
    const int l16 = lane & 15, qd = lane >> 4;

    const int m0 = mb * 64;
    const int n0 = (nblk * 4 + wave) * 64;   // wave-private 64x64 tile

    const bf16_t* arow[4];
    const bf16_t* brow[4];
#pragma unroll
    for (int i = 0; i < 4; ++i)
        arow[i] = h + (size_t)(m0 + i * 16 + l16) * H_SZ + qd * 8;
#pragma unroll
    for (int j = 0; j < 4; ++j)
        brow[j] = w2t + ((size_t)p * D_SZ + n0 + j * 16 + l16) * H_SZ + qd * 8;

    f32x4 acc[4][4];
#pragma unroll
    for (int i = 0; i < 4; ++i)
#pragma unroll
        for (int j = 0; j < 4; ++j)
            acc[i][j] = (f32x4){0.f, 0.f, 0.f, 0.f};

    for (int kt = 0; kt < H_SZ; kt += 32) {
        bf16x8 af[4], bfv[4];
#pragma unroll
        for (int i = 0; i < 4; ++i) af[i] = *(const bf16x8*)(arow[i] + kt);
#pragma unroll
        for (int j = 0; j < 4; ++j) bfv[j] = *(const bf16x8*)(brow[j] + kt);
#pragma unroll
        for (int i = 0; i < 4; ++i)
#pragma unroll
            for (int j = 0; j < 4; ++j)
                acc[i][j] = __builtin_amdgcn_mfma_f32_16x16x32_bf16(af[i], bfv[j], acc[i][j], 0, 0, 0);
    }

    // epilogue: bias, scatter to original rows; pad rows masked
#pragma unroll
    for (int i = 0; i < 4; ++i) {
#pragma unroll
        for (int r = 0; r < 4; ++r) {
            int ml = i * 16 + qd * 4 + r;
            int g = rowidx[m0 + ml];
            if (g >= 0) {
                size_t orow = (size_t)g * D_SZ;
#pragma unroll
                for (int j = 0; j < 4; ++j) {
                    int n = n0 + j * 16 + l16;
                    out[orow + n] = acc[i][j][r] + b2[p * D_SZ + n];
                }
            }
        }
    }
}

// ---------------- launch ----------------

extern "C" void kernel_launch(void* const* d_in, const int* in_sizes, int n_in,
                              void* d_out, int out_size, void* d_ws, size_t ws_size,
                              hipStream_t stream) {
    const float* latents = (const float*)d_in[0];
    const float* actions = (const float*)d_in[1];
    const int*   pol     = (const int*)d_in[2];
    const float* W1      = (const float*)d_in[3];
    const float* b1      = (const float*)d_in[4];
    const float* W2      = (const float*)d_in[5];
    const float* b2      = (const float*)d_in[6];
    float* out = (float*)d_out;

    char* ws = (char*)d_ws;
    int* counts    = (int*)ws;
    int* cursors   = counts + P_SZ;
    int* blk_p     = cursors + P_SZ;
    int* blockhist = blk_p + MB_MAX;
    int* rowidx    = blockhist + NSEG * P_SZ;
    size_t pos = ((size_t)(2 * P_SZ + MB_MAX + NSEG * P_SZ + BPAD) * sizeof(int) + 255) & ~(size_t)255;
    bf16_t* xs  = (bf16_t*)(ws + pos);  pos += (size_t)BPAD * K1 * 2;
    bf16_t* hbuf= (bf16_t*)(ws + pos);  pos += (size_t)BPAD * H_SZ * 2;
    bf16_t* w1t = (bf16_t*)(ws + pos);  pos += (size_t)P_SZ * H_SZ * K1 * 2;
    bf16_t* w2t = (bf16_t*)(ws + pos);  pos += (size_t)P_SZ * D_SZ * H_SZ * 2;

    hist_block<<<NSEG, 256, 0, stream>>>(pol, blockhist, rowidx);
    prefix_kernel<<<1, 256, 0, stream>>>(blockhist, counts, cursors, blk_p);
    scatter_agg<<<NSEG, 256, 0, stream>>>(pol, cursors, rowidx);
    prep_all<<<PREP_BLOCKS + TR1_BLOCKS + TR2_BLOCKS, 256, 0, stream>>>(
        latents, actions, rowidx, W1, W2, xs, w1t, w2t);
    gemm1_kernel<<<G1_GRID, 256, 0, stream>>>(xs, w1t, b1, blk_p, hbuf);
    gemm2_kernel<<<G2_GRID, 256, 0, stream>>>(hbuf, w2t, b2, blk_p, rowidx, out);
}

// Round 9
// 222.686 us; speedup vs baseline: 1.3927x; 1.3927x over previous
//
#include <hip/hip_runtime.h>
#include <hip/hip_bf16.h>
#include <stdint.h>

#define B_SZ 16384
#define P_SZ 8
#define D_SZ 512
#define A_SZ 64
#define K1 576    // D + A
#define H_SZ 1024
#define NSEG 64
#define MB_MAX 72               // max 256-row m-blocks after per-policy padding
#define BPAD (B_SZ + P_SZ*256)  // 18432 padded sorted-row capacity
#define TR1_BLOCKS (P_SZ * 9 * 16)      // 1152  (576/64 x 1024/64)
#define TR2_BLOCKS (P_SZ * 16 * 8)      // 1024  (1024/64 x 512/64)
#define G1_GRID (BPAD / 128 * (H_SZ / 64))    // 2304
#define G2_GRID (BPAD / 128 * (D_SZ / 64))    // 1152

typedef __bf16 bf16_t;
typedef __bf16 bf16x8 __attribute__((ext_vector_type(8)));
typedef float f32x4 __attribute__((ext_vector_type(4)));

__device__ __forceinline__ void glds16(const void* g, void* l) {
    __builtin_amdgcn_global_load_lds(
        (const __attribute__((address_space(1))) unsigned*)g,
        (__attribute__((address_space(3))) unsigned*)l, 16, 0, 0);
}

// ---------------- sort prep ----------------

__global__ __launch_bounds__(256) void hist_block(const int* __restrict__ pol,
                                                  int* __restrict__ blockhist,
                                                  int* __restrict__ rowidx) {
    __shared__ int lc[P_SZ];
    int t = threadIdx.x;
    if (t < P_SZ) lc[t] = 0;
    __syncthreads();
    int gid = blockIdx.x * 256 + t;
    rowidx[gid] = -1;
    if (gid < BPAD - B_SZ) rowidx[B_SZ + gid] = -1;
    atomicAdd(&lc[pol[gid]], 1);
    __syncthreads();
    if (t < P_SZ) blockhist[blockIdx.x * P_SZ + t] = lc[t];
}

// parallel reduction (was: 64 serial dependent global reads on one thread)
__global__ __launch_bounds__(256) void prefix_kernel(const int* __restrict__ blockhist,
                                                     int* __restrict__ counts,
                                                     int* __restrict__ cursors,
                                                     int* __restrict__ blk_p) {
    __shared__ int csh[P_SZ];
    int t = threadIdx.x;
    int p = t >> 5, i = t & 31;          // 8 policies x 32 lanes
    int s = blockhist[i * P_SZ + p] + blockhist[(i + 32) * P_SZ + p];
#pragma unroll
    for (int m = 16; m >= 1; m >>= 1) s += __shfl_xor(s, m, 32);
    if (i == 0) csh[p] = s;
    __syncthreads();
    if (t == 0) {
        int run = 0;
        for (int pp = 0; pp < P_SZ; ++pp) {
            counts[pp] = csh[pp];
            cursors[pp] = run;
            run += ((csh[pp] + 255) >> 8) * 256;
        }
    }
    if (t < MB_MAX) {
        int run = 0, val = -1;
#pragma unroll
        for (int pp = 0; pp < P_SZ; ++pp) {
            int nb = (csh[pp] + 255) >> 8;
            if (t >= run && t < run + nb) val = pp;
            run += nb;
        }
        blk_p[t] = val;
    }
}

__global__ __launch_bounds__(256) void scatter_agg(const int* __restrict__ pol,
                                                   int* __restrict__ cursors,
                                                   int* __restrict__ rowidx) {
    __shared__ int lc[P_SZ], base_s[P_SZ];
    int t = threadIdx.x;
    if (t < P_SZ) lc[t] = 0;
    __syncthreads();
    int i = blockIdx.x * 256 + t;
    int p = pol[i];
    int lpos = atomicAdd(&lc[p], 1);
    __syncthreads();
    if (t < P_SZ) base_s[t] = atomicAdd(&cursors[t], lc[t]);
    __syncthreads();
    rowidx[base_s[p] + lpos] = i;
}

// ---------------- prep_w: weight transposes only (x-gather now fused into gemm1) ----

__global__ __launch_bounds__(256) void prep_w(const float* __restrict__ W1,
                                              const float* __restrict__ W2,
                                              bf16_t* __restrict__ w1t,
                                              bf16_t* __restrict__ w2t) {
    int tz = blockIdx.x;
    int tid = threadIdx.x;
    const float* Wp; bf16_t* WTp; int K, N, k0, n0;
    if (tz < TR1_BLOCKS) {
        int p = tz / 144, rem = tz % 144;    // 9 k-tiles x 16 n-tiles
        k0 = (rem / 16) * 64; n0 = (rem % 16) * 64;
        K = K1; N = H_SZ;
        Wp = W1 + (size_t)p * K1 * H_SZ;
        WTp = w1t + (size_t)p * H_SZ * K1;
    } else {
        int u = tz - TR1_BLOCKS;
        int p = u / 128, rem = u % 128;      // 16 k-tiles x 8 n-tiles
        k0 = (rem / 8) * 64; n0 = (rem % 8) * 64;
        K = H_SZ; N = D_SZ;
        Wp = W2 + (size_t)p * H_SZ * D_SZ;
        WTp = w2t + (size_t)p * D_SZ * H_SZ;
    }
    __shared__ float ls[64][65];
#pragma unroll
    for (int e = 0; e < 4; ++e) {
        int idx = e * 256 + tid;
        int kk = idx >> 4, nn = (idx & 15) * 4;
        f32x4 v = *(const f32x4*)&Wp[(size_t)(k0 + kk) * N + n0 + nn];
        ls[kk][nn]     = v[0];
        ls[kk][nn + 1] = v[1];
        ls[kk][nn + 2] = v[2];
        ls[kk][nn + 3] = v[3];
    }
    __syncthreads();
#pragma unroll
    for (int e = 0; e < 2; ++e) {
        int idx = e * 256 + tid;
        int nn = idx >> 3, ks = (idx & 7) * 8;
        bf16x8 o;
#pragma unroll
        for (int q = 0; q < 8; ++q) o[q] = (bf16_t)ls[ks + q][nn];
        *(bf16x8*)&WTp[(size_t)(n0 + nn) * K + k0 + ks] = o;
    }
}

// ---------------- GEMMs -------------------------------------------------------------
// GEMM floor established (rounds 0-8): 2-barrier LDS loop ~ 40us/GEMM invariant
// across tiling/occupancy/pipelining; register-direct (R8) 2.4x worse. This round
// keeps the floor structure and instead DELETES the x-gather prep pass: gemm1
// stages A directly from latents/actions (per-lane glds16 global addresses do the
// rowidx gather; LDS holds f32, frags converted to bf16 at read). K split: iters
// 0-7 = latents cols, iter 8 = actions (exactly 64 f32). Pad rows clamp to row 0;
// garbage flows only into pad output rows (MFMA is row-local), masked by gemm2's
// epilogue. A-chunk swizzle for 8-chunk f32 rows: stored kc = logical kc ^ (r&7)
// (bijective per row; frag = 2 x ds_read_b128 at the LDS port floor).

__global__ __launch_bounds__(256, 4) void gemm1_kernel(
    const float* __restrict__ latents, const float* __restrict__ actions,
    const int* __restrict__ rowidx, const bf16_t* __restrict__ w1t,
    const float* __restrict__ b1, const int* __restrict__ blk_p,
    bf16_t* __restrict__ h) {

    const int b = blockIdx.x;
    const int wid = (b & 7) * (G1_GRID / 8) + (b >> 3);   // XCD-contiguous work id
    const int mb = wid >> 4;          // 0..143  (n fastest within an XCD)
    const int nb = wid & 15;          // 0..15
    const int p = blk_p[mb >> 1];
    if (p < 0) return;
    const int m0 = mb * 128;
    const int n0 = nb * 64;

    constexpr int ASUB = 128 * 32;      // f32 elems per 32-k subtile (16 KB)
    constexpr int BSUB = 64 * 32;       // bf16 elems per subtile (4 KB)
    __shared__ __align__(16) float  As[2 * ASUB];   // 32 KB
    __shared__ __align__(16) bf16_t Bs[2 * BSUB];   // 8 KB

    const int tid = threadIdx.x;
    const int wave = tid >> 6, lane = tid & 63;

    // A: per subtile 1024 chunks (16B = 4 f32), 16 slots of 64; wave: slots wave*4+ss
    const float* a_lat[4]; const float* a_act[4]; float* a_dst[4];
#pragma unroll
    for (int ss = 0; ss < 4; ++ss) {
        int c = (wave * 4 + ss) * 64 + lane;
        int r = c >> 3;                       // row 0..127
        int kc = (c & 7) ^ (r & 7);           // logical chunk within 32-f32 subtile
        int g = rowidx[m0 + r]; if (g < 0) g = 0;   // pad rows: clamp (masked later)
        a_lat[ss] = latents + (size_t)g * D_SZ + kc * 4;
        a_act[ss] = actions + (size_t)g * A_SZ + kc * 4;
        a_dst[ss] = As + c * 4;               // c*16B, linear (glds16 dst)
    }
    // B: per subtile 256 bf16-chunks, 4 slots; wave handles slot `wave` (as R7)
    const bf16_t* b_src[2]; bf16_t* b_dst[2];
#pragma unroll
    for (int hh = 0; hh < 2; ++hh) {
        int c = wave * 64 + lane;
        int r = c >> 2;
        int kl = (c & 3) ^ ((r >> 1) & 3);
        b_src[hh] = w1t + ((size_t)p * H_SZ + n0 + r) * K1 + hh * 32 + kl * 8;
        b_dst[hh] = Bs + hh * BSUB + c * 8;
    }

    const int l16 = lane & 15, qd = lane >> 4;
    const int bswz = (l16 >> 1) & 3;
    const int akey = l16 & 7;                 // = (A row)&7 for all frags
    const int wr = wave >> 1, wc = wave & 1;  // 2x2 wave grid; wave tile 64x32
    int aoff0[4], aoff1[4], boff[2];
#pragma unroll
    for (int i = 0; i < 4; ++i) {
        int row = wr * 64 + i * 16 + l16;
        aoff0[i] = row * 32 + (((2 * qd)     ^ akey) * 4);   // f32 units
        aoff1[i] = row * 32 + (((2 * qd + 1) ^ akey) * 4);
    }
#pragma unroll
    for (int j = 0; j < 2; ++j) boff[j] = (wc * 32 + j * 16 + l16) * 32 + ((qd ^ bswz) * 8);

    f32x4 acc[4][2];
#pragma unroll
    for (int i = 0; i < 4; ++i)
#pragma unroll
        for (int j = 0; j < 2; ++j)
            acc[i][j] = (f32x4){0.f, 0.f, 0.f, 0.f};

    for (int t = 0; t < 9; ++t) {
        __syncthreads();   // previous iter's frags consumed
        const bool act = (t == 8);            // k 512..575 -> actions (64 f32)
        const int k0 = t * 64;
#pragma unroll
        for (int hh = 0; hh < 2; ++hh) {
#pragma unroll
            for (int ss = 0; ss < 4; ++ss) {
                const float* s = act ? (a_act[ss] + hh * 32)
                                     : (a_lat[ss] + k0 + hh * 32);
                glds16(s, a_dst[ss] + hh * ASUB);
            }
            glds16(b_src[hh] + k0, b_dst[hh]);
        }
        __syncthreads();   // staging complete (compiler inserts vmcnt(0))
#pragma unroll
        for (int hh = 0; hh < 2; ++hh) {
            bf16x8 af[4]; bf16x8 bfv[2];
#pragma unroll
            for (int i = 0; i < 4; ++i) {
                f32x4 lo = *(const f32x4*)(As + hh * ASUB + aoff0[i]);
                f32x4 hi = *(const f32x4*)(As + hh * ASUB + aoff1[i]);
                af[i][0] = (bf16_t)lo[0]; af[i][1] = (bf16_t)lo[1];
                af[i][2] = (bf16_t)lo[2]; af[i][3] = (bf16_t)lo[3];
                af[i][4] = (bf16_t)hi[0]; af[i][5] = (bf16_t)hi[1];
                af[i][6] = (bf16_t)hi[2]; af[i][7] = (bf16_t)hi[3];
            }
#pragma unroll
            for (int j = 0; j < 2; ++j) bfv[j] = *(const bf16x8*)(Bs + hh * BSUB + boff[j]);
#pragma unroll
            for (int i = 0; i < 4; ++i)
#pragma unroll
                for (int j = 0; j < 2; ++j)
                    acc[i][j] = __builtin_amdgcn_mfma_f32_16x16x32_bf16(af[i], bfv[j], acc[i][j], 0, 0, 0);
        }
    }

    // epilogue: bias + relu -> h (padded sorted layout)
#pragma unroll
    for (int i = 0; i < 4; ++i) {
#pragma unroll
        for (int r = 0; r < 4; ++r) {
            int ml = wr * 64 + i * 16 + qd * 4 + r;     // C/D: row = quad*4 + reg
            size_t row = (size_t)(m0 + ml);
#pragma unroll
            for (int j = 0; j < 2; ++j) {
                int n = n0 + wc * 32 + j * 16 + l16;    // C/D: col = lane&15
                float v = acc[i][j][r] + b1[p * H_SZ + n];
                h[row * H_SZ + n] = (bf16_t)fmaxf(v, 0.f);
            }
        }
    }
}

__global__ __launch_bounds__(256, 6) void gemm2_kernel(
    const bf16_t* __restrict__ h, const bf16_t* __restrict__ w2t,
    const float* __restrict__ b2, const int* __restrict__ blk_p,
    const int* __restrict__ rowidx, float* __restrict__ out) {

    const int b = blockIdx.x;
    const int wid = (b & 7) * (G2_GRID / 8) + (b >> 3);   // XCD-contiguous work id
    const int mb = wid >> 3;
    const int nb = wid & 7;
    const int p = blk_p[mb >> 1];
    if (p < 0) return;
    const int m0 = mb * 128;
    const int n0 = nb * 64;

    constexpr int ASUB = 128 * 32;                   // A subtile elems
    constexpr int BSUB = 64 * 32;                    // B subtile elems
    __shared__ __align__(16) bf16_t As[2 * ASUB];    // 16 KB
    __shared__ __align__(16) bf16_t Bs[2 * BSUB];    // 8 KB

    const int tid = threadIdx.x;
    const int wave = tid >> 6, lane = tid & 63;

    // A: per subtile 512 chunks, 8 slots; wave handles slots wave*2+i
    const bf16_t *a_src[2][2]; bf16_t *a_dst[2][2];
#pragma unroll
    for (int hh = 0; hh < 2; ++hh)
#pragma unroll
        for (int i = 0; i < 2; ++i) {
            int c = (wave * 2 + i) * 64 + lane;
            int r = c >> 2;
            int kl = (c & 3) ^ ((r >> 1) & 3);
            a_src[hh][i] = h + (size_t)(m0 + r) * H_SZ + hh * 32 + kl * 8;
            a_dst[hh][i] = As + hh * ASUB + c * 8;
        }
    // B: per subtile 256 chunks, 4 slots; wave handles slot `wave`
    const bf16_t *b_src[2]; bf16_t *b_dst[2];
#pragma unroll
    for (int hh = 0; hh < 2; ++hh) {
        int c = wave * 64 + lane;
        int r = c >> 2;
        int kl = (c & 3) ^ ((r >> 1) & 3);
        b_src[hh] = w2t + ((size_t)p * D_SZ + n0 + r) * H_SZ + hh * 32 + kl * 8;
        b_dst[hh] = Bs + hh * BSUB + c * 8;
    }

    const int l16 = lane & 15, qd = lane >> 4;
    const int swz = (l16 >> 1) & 3;
    const int wr = wave >> 1, wc = wave & 1;   // 2x2 wave grid; wave tile 64x32
    int aoff[4], boff[2];
#pragma unroll
    for (int i = 0; i < 4; ++i) aoff[i] = (wr * 64 + i * 16 + l16) * 32 + ((qd ^ swz) * 8);
#pragma unroll
    for (int j = 0; j < 2; ++j) boff[j] = (wc * 32 + j * 16 + l16) * 32 + ((qd ^ swz) * 8);

    f32x4 acc[4][2];
#pragma unroll
    for (int i = 0; i < 4; ++i)
#pragma unroll
        for (int j = 0; j < 2; ++j)
            acc[i][j] = (f32x4){0.f, 0.f, 0.f, 0.f};

    for (int kt = 0; kt < H_SZ; kt += 64) {
        __syncthreads();
#pragma unroll
        for (int hh = 0; hh < 2; ++hh) {
#pragma unroll
            for (int i = 0; i < 2; ++i) glds16(a_src[hh][i] + kt, a_dst[hh][i]);
            glds16(b_src[hh] + kt, b_dst[hh]);
        }
        __syncthreads();
#pragma unroll
        for (int hh = 0; hh < 2; ++hh) {
            bf16x8 af[4], bfv[2];
#pragma unroll
            for (int i = 0; i < 4; ++i) af[i] = *(const bf16x8*)(As + hh * ASUB + aoff[i]);
#pragma unroll
            for (int j = 0; j < 2; ++j) bfv[j] = *(const bf16x8*)(Bs + hh * BSUB + boff[j]);
#pragma unroll
            for (int i = 0; i < 4; ++i)
#pragma unroll
                for (int j = 0; j < 2; ++j)
                    acc[i][j] = __builtin_amdgcn_mfma_f32_16x16x32_bf16(af[i], bfv[j], acc[i][j], 0, 0, 0);
        }
    }

    // epilogue: bias, scatter to original rows; pad rows masked
#pragma unroll
    for (int i = 0; i < 4; ++i) {
#pragma unroll
        for (int r = 0; r < 4; ++r) {
            int ml = wr * 64 + i * 16 + qd * 4 + r;
            int g = rowidx[m0 + ml];
            if (g >= 0) {
                size_t orow = (size_t)g * D_SZ;
#pragma unroll
                for (int j = 0; j < 2; ++j) {
                    int n = n0 + wc * 32 + j * 16 + l16;
                    out[orow + n] = acc[i][j][r] + b2[p * D_SZ + n];
                }
            }
        }
    }
}

// ---------------- launch ----------------

extern "C" void kernel_launch(void* const* d_in, const int* in_sizes, int n_in,
                              void* d_out, int out_size, void* d_ws, size_t ws_size,
                              hipStream_t stream) {
    const float* latents = (const float*)d_in[0];
    const float* actions = (const float*)d_in[1];
    const int*   pol     = (const int*)d_in[2];
    const float* W1      = (const float*)d_in[3];
    const float* b1      = (const float*)d_in[4];
    const float* W2      = (const float*)d_in[5];
    const float* b2      = (const float*)d_in[6];
    float* out = (float*)d_out;

    char* ws = (char*)d_ws;
    int* counts    = (int*)ws;
    int* cursors   = counts + P_SZ;
    int* blk_p     = cursors + P_SZ;
    int* blockhist = blk_p + MB_MAX;
    int* rowidx    = blockhist + NSEG * P_SZ;
    size_t pos = ((size_t)(2 * P_SZ + MB_MAX + NSEG * P_SZ + BPAD) * sizeof(int) + 255) & ~(size_t)255;
    bf16_t* hbuf= (bf16_t*)(ws + pos);  pos += (size_t)BPAD * H_SZ * 2;
    bf16_t* w1t = (bf16_t*)(ws + pos);  pos += (size_t)P_SZ * H_SZ * K1 * 2;
    bf16_t* w2t = (bf16_t*)(ws + pos);  pos += (size_t)P_SZ * D_SZ * H_SZ * 2;

    hist_block<<<NSEG, 256, 0, stream>>>(pol, blockhist, rowidx);
    prefix_kernel<<<1, 256, 0, stream>>>(blockhist, counts, cursors, blk_p);
    scatter_agg<<<NSEG, 256, 0, stream>>>(pol, cursors, rowidx);
    prep_w<<<TR1_BLOCKS + TR2_BLOCKS, 256, 0, stream>>>(W1, W2, w1t, w2t);
    gemm1_kernel<<<G1_GRID, 256, 0, stream>>>(latents, actions, rowidx, w1t, b1, blk_p, hbuf);
    gemm2_kernel<<<G2_GRID, 256, 0, stream>>>(hbuf, w2t, b2, blk_p, rowidx, out);
}

// Round 12
// 210.440 us; speedup vs baseline: 1.4737x; 1.0582x over previous
//
#include <hip/hip_runtime.h>
#include <hip/hip_bf16.h>
#include <stdint.h>

#define B_SZ 16384
#define P_SZ 8
#define D_SZ 512
#define A_SZ 64
#define K1 576    // D + A
#define H_SZ 1024
#define NSEG 64
#define MB_MAX 72               // max 256-row m-blocks after per-policy padding
#define BPAD (B_SZ + P_SZ*256)  // 18432 padded sorted-row capacity
#define TR1_BLOCKS (P_SZ * 9 * 16)      // 1152  (576/64 x 1024/64)
#define TR2_BLOCKS (P_SZ * 16 * 8)      // 1024  (1024/64 x 512/64)
#define G1_GRID (BPAD / 128 * (H_SZ / 64))    // 2304
#define G2_GRID (BPAD / 128 * (D_SZ / 64))    // 1152

typedef __bf16 bf16_t;
typedef __bf16 bf16x8 __attribute__((ext_vector_type(8)));
typedef float f32x4 __attribute__((ext_vector_type(4)));

__device__ __forceinline__ void glds16(const void* g, void* l) {
    __builtin_amdgcn_global_load_lds(
        (const __attribute__((address_space(1))) unsigned*)g,
        (__attribute__((address_space(3))) unsigned*)l, 16, 0, 0);
}

// ---------------- sort prep ----------------

__global__ __launch_bounds__(256) void hist_block(const int* __restrict__ pol,
                                                  int* __restrict__ blockhist,
                                                  int* __restrict__ rowidx) {
    __shared__ int lc[P_SZ];
    int t = threadIdx.x;
    if (t < P_SZ) lc[t] = 0;
    __syncthreads();
    int gid = blockIdx.x * 256 + t;
    rowidx[gid] = -1;
    if (gid < BPAD - B_SZ) rowidx[B_SZ + gid] = -1;
    atomicAdd(&lc[pol[gid]], 1);
    __syncthreads();
    if (t < P_SZ) blockhist[blockIdx.x * P_SZ + t] = lc[t];
}

// parallel reduction (was: 64 serial dependent global reads on one thread)
__global__ __launch_bounds__(256) void prefix_kernel(const int* __restrict__ blockhist,
                                                     int* __restrict__ counts,
                                                     int* __restrict__ cursors,
                                                     int* __restrict__ blk_p) {
    __shared__ int csh[P_SZ];
    int t = threadIdx.x;
    int p = t >> 5, i = t & 31;          // 8 policies x 32 lanes
    int s = blockhist[i * P_SZ + p] + blockhist[(i + 32) * P_SZ + p];
#pragma unroll
    for (int m = 16; m >= 1; m >>= 1) s += __shfl_xor(s, m, 32);
    if (i == 0) csh[p] = s;
    __syncthreads();
    if (t == 0) {
        int run = 0;
        for (int pp = 0; pp < P_SZ; ++pp) {
            counts[pp] = csh[pp];
            cursors[pp] = run;
            run += ((csh[pp] + 255) >> 8) * 256;
        }
    }
    if (t < MB_MAX) {
        int run = 0, val = -1;
#pragma unroll
        for (int pp = 0; pp < P_SZ; ++pp) {
            int nb = (csh[pp] + 255) >> 8;
            if (t >= run && t < run + nb) val = pp;
            run += nb;
        }
        blk_p[t] = val;
    }
}

__global__ __launch_bounds__(256) void scatter_agg(const int* __restrict__ pol,
                                                   int* __restrict__ cursors,
                                                   int* __restrict__ rowidx) {
    __shared__ int lc[P_SZ], base_s[P_SZ];
    int t = threadIdx.x;
    if (t < P_SZ) lc[t] = 0;
    __syncthreads();
    int i = blockIdx.x * 256 + t;
    int p = pol[i];
    int lpos = atomicAdd(&lc[p], 1);
    __syncthreads();
    if (t < P_SZ) base_s[t] = atomicAdd(&cursors[t], lc[t]);
    __syncthreads();
    rowidx[base_s[p] + lpos] = i;
}

// ---------------- prep_w: weight transposes only (x-gather fused into gemm1) --------

__global__ __launch_bounds__(256) void prep_w(const float* __restrict__ W1,
                                              const float* __restrict__ W2,
                                              bf16_t* __restrict__ w1t,
                                              bf16_t* __restrict__ w2t) {
    int tz = blockIdx.x;
    int tid = threadIdx.x;
    const float* Wp; bf16_t* WTp; int K, N, k0, n0;
    if (tz < TR1_BLOCKS) {
        int p = tz / 144, rem = tz % 144;    // 9 k-tiles x 16 n-tiles
        k0 = (rem / 16) * 64; n0 = (rem % 16) * 64;
        K = K1; N = H_SZ;
        Wp = W1 + (size_t)p * K1 * H_SZ;
        WTp = w1t + (size_t)p * H_SZ * K1;
    } else {
        int u = tz - TR1_BLOCKS;
        int p = u / 128, rem = u % 128;      // 16 k-tiles x 8 n-tiles
        k0 = (rem / 8) * 64; n0 = (rem % 8) * 64;
        K = H_SZ; N = D_SZ;
        Wp = W2 + (size_t)p * H_SZ * D_SZ;
        WTp = w2t + (size_t)p * D_SZ * H_SZ;
    }
    __shared__ float ls[64][65];
#pragma unroll
    for (int e = 0; e < 4; ++e) {
        int idx = e * 256 + tid;
        int kk = idx >> 4, nn = (idx & 15) * 4;
        f32x4 v = *(const f32x4*)&Wp[(size_t)(k0 + kk) * N + n0 + nn];
        ls[kk][nn]     = v[0];
        ls[kk][nn + 1] = v[1];
        ls[kk][nn + 2] = v[2];
        ls[kk][nn + 3] = v[3];
    }
    __syncthreads();
#pragma unroll
    for (int e = 0; e < 2; ++e) {
        int idx = e * 256 + tid;
        int nn = idx >> 3, ks = (idx & 7) * 8;
        bf16x8 o;
#pragma unroll
        for (int q = 0; q < 8; ++q) o[q] = (bf16_t)ls[ks + q][nn];
        *(bf16x8*)&WTp[(size_t)(n0 + nn) * K + k0 + ks] = o;
    }
}

// ---------------- GEMMs -------------------------------------------------------------
// Fusion (R9-verified): gemm1 gathers A directly from latents/actions (x-gather pass
// deleted; FETCH dropped as predicted). R9's f32-in-LDS layout caused 4.9M bank
// conflicts; fix = stage through registers with f32->bf16 cvt and ds_write_b128 into
// EXACTLY R7's bf16 layout (measured 0 conflicts). HEDGE vs R10/R11 infra failures:
// gemm1 now stages BOTH A and B via registers -- no glds16 in gemm1 at all, removing
// the one never-passed pattern (mixed ds_write + glds16 outstanding at one barrier).
// ds_writes are tid-contiguous 16B -> sequential banks, conflict-free by construction.
// gemm2 byte-identical to its R9-passing form (glds16, <=41us measured).

__global__ __launch_bounds__(256, 4) void gemm1_kernel(
    const float* __restrict__ latents, const float* __restrict__ actions,
    const int* __restrict__ rowidx, const bf16_t* __restrict__ w1t,
    const float* __restrict__ b1, const int* __restrict__ blk_p,
    bf16_t* __restrict__ h) {

    const int b = blockIdx.x;
    const int wid = (b & 7) * (G1_GRID / 8) + (b >> 3);   // XCD-contiguous work id
    const int mb = wid >> 4;          // 0..143  (n fastest within an XCD)
    const int nb = wid & 15;          // 0..15
    const int p = blk_p[mb >> 1];
    if (p < 0) return;
    const int m0 = mb * 128;
    const int n0 = nb * 64;

    constexpr int ASUB = 128 * 32;      // bf16 elems per 32-k subtile (8 KB)
    constexpr int BSUB = 64 * 32;       // bf16 elems per subtile (4 KB)
    __shared__ __align__(16) bf16_t As[2 * ASUB];   // 16 KB
    __shared__ __align__(16) bf16_t Bs[2 * BSUB];   // 8 KB

    const int tid = threadIdx.x;
    const int wave = tid >> 6, lane = tid & 63;

    // A reg-staged: per subtile 512 bf16-chunks (16B); thread handles c = tid, tid+256.
    // Chunk c: row r = c>>2, stored pos (c&3) holds logical chunk (c&3)^((r>>1)&3)
    // (R7 layout). Global source: gathered row g = rowidx[m0+r] (pad rows clamp to 0;
    // garbage flows only to pad h rows, masked by gemm2's epilogue).
    const float* a_lat[2]; const float* a_act[2]; bf16_t* a_dst[2];
#pragma unroll
    for (int cc = 0; cc < 2; ++cc) {
        int c = tid + cc * 256;
        int r = c >> 2;
        int kl = (c & 3) ^ ((r >> 1) & 3);
        int g = rowidx[m0 + r]; if (g < 0) g = 0;
        a_lat[cc] = latents + (size_t)g * D_SZ + kl * 8;
        a_act[cc] = actions + (size_t)g * A_SZ + kl * 8;
        a_dst[cc] = As + c * 8;               // + hh*ASUB
    }
    // B reg-staged: per subtile 256 chunks; thread handles chunk c = tid (bf16x8 load)
    const bf16_t* b_src; bf16_t* b_dst;
    {
        int c = tid;
        int r = c >> 2;
        int kl = (c & 3) ^ ((r >> 1) & 3);
        b_src = w1t + ((size_t)p * H_SZ + n0 + r) * K1 + kl * 8;
        b_dst = Bs + c * 8;                   // + hh*BSUB
    }

    const int l16 = lane & 15, qd = lane >> 4;
    const int swz = (l16 >> 1) & 3;
    const int wr = wave >> 1, wc = wave & 1;   // 2x2 wave grid; wave tile 64x32
    int aoff[4], boff[2];
#pragma unroll
    for (int i = 0; i < 4; ++i) aoff[i] = (wr * 64 + i * 16 + l16) * 32 + ((qd ^ swz) * 8);
#pragma unroll
    for (int j = 0; j < 2; ++j) boff[j] = (wc * 32 + j * 16 + l16) * 32 + ((qd ^ swz) * 8);

    f32x4 acc[4][2];
#pragma unroll
    for (int i = 0; i < 4; ++i)
#pragma unroll
        for (int j = 0; j < 2; ++j)
            acc[i][j] = (f32x4){0.f, 0.f, 0.f, 0.f};

    for (int t = 0; t < 9; ++t) {
        const bool act = (t == 8);            // k 512..575 -> actions (64 f32)
        // stage A: global f32 -> regs -> bf16 -> LDS (R7 bf16 layout)
#pragma unroll
        for (int cc = 0; cc < 2; ++cc)
#pragma unroll
            for (int hh = 0; hh < 2; ++hh) {
                const float* s = act ? (a_act[cc] + hh * 32)
                                     : (a_lat[cc] + t * 64 + hh * 32);
                f32x4 lo = *(const f32x4*)s;
                f32x4 hi = *(const f32x4*)(s + 4);
                bf16x8 o;
                o[0] = (bf16_t)lo[0]; o[1] = (bf16_t)lo[1];
                o[2] = (bf16_t)lo[2]; o[3] = (bf16_t)lo[3];
                o[4] = (bf16_t)hi[0]; o[5] = (bf16_t)hi[1];
                o[6] = (bf16_t)hi[2]; o[7] = (bf16_t)hi[3];
                *(bf16x8*)(a_dst[cc] + hh * ASUB) = o;
            }
        // stage B: global bf16x8 -> regs -> LDS
#pragma unroll
        for (int hh = 0; hh < 2; ++hh) {
            bf16x8 v = *(const bf16x8*)(b_src + t * 64 + hh * 32);
            *(bf16x8*)(b_dst + hh * BSUB) = v;
        }
        __syncthreads();   // all ds_writes visible (lgkmcnt drained)
#pragma unroll
        for (int hh = 0; hh < 2; ++hh) {
            bf16x8 af[4], bfv[2];
#pragma unroll
            for (int i = 0; i < 4; ++i) af[i] = *(const bf16x8*)(As + hh * ASUB + aoff[i]);
#pragma unroll
            for (int j = 0; j < 2; ++j) bfv[j] = *(const bf16x8*)(Bs + hh * BSUB + boff[j]);
#pragma unroll
            for (int i = 0; i < 4; ++i)
#pragma unroll
                for (int j = 0; j < 2; ++j)
                    acc[i][j] = __builtin_amdgcn_mfma_f32_16x16x32_bf16(af[i], bfv[j], acc[i][j], 0, 0, 0);
        }
        __syncthreads();   // frags consumed before next iter's writes
    }

    // epilogue: bias + relu -> h (padded sorted layout)
#pragma unroll
    for (int i = 0; i < 4; ++i) {
#pragma unroll
        for (int r = 0; r < 4; ++r) {
            int ml = wr * 64 + i * 16 + qd * 4 + r;     // C/D: row = quad*4 + reg
            size_t row = (size_t)(m0 + ml);
#pragma unroll
            for (int j = 0; j < 2; ++j) {
                int n = n0 + wc * 32 + j * 16 + l16;    // C/D: col = lane&15
                float v = acc[i][j][r] + b1[p * H_SZ + n];
                h[row * H_SZ + n] = (bf16_t)fmaxf(v, 0.f);
            }
        }
    }
}

__global__ __launch_bounds__(256, 6) void gemm2_kernel(
    const bf16_t* __restrict__ h, const bf16_t* __restrict__ w2t,
    const float* __restrict__ b2, const int* __restrict__ blk_p,
    const int* __restrict__ rowidx, float* __restrict__ out) {

    const int b = blockIdx.x;
    const int wid = (b & 7) * (G2_GRID / 8) + (b >> 3);   // XCD-contiguous work id
    const int mb = wid >> 3;
    const int nb = wid & 7;
    const int p = blk_p[mb >> 1];
    if (p < 0) return;
    const int m0 = mb * 128;
    const int n0 = nb * 64;

    constexpr int ASUB = 128 * 32;                   // A subtile elems
    constexpr int BSUB = 64 * 32;                    // B subtile elems
    __shared__ __align__(16) bf16_t As[2 * ASUB];    // 16 KB
    __shared__ __align__(16) bf16_t Bs[2 * BSUB];    // 8 KB

    const int tid = threadIdx.x;
    const int wave = tid >> 6, lane = tid & 63;

    // A: per subtile 512 chunks, 8 slots; wave handles slots wave*2+i
    const bf16_t *a_src[2][2]; bf16_t *a_dst[2][2];
#pragma unroll
    for (int hh = 0; hh < 2; ++hh)
#pragma unroll
        for (int i = 0; i < 2; ++i) {
            int c = (wave * 2 + i) * 64 + lane;
            int r = c >> 2;
            int kl = (c & 3) ^ ((r >> 1) & 3);
            a_src[hh][i] = h + (size_t)(m0 + r) * H_SZ + hh * 32 + kl * 8;
            a_dst[hh][i] = As + hh * ASUB + c * 8;
        }
    // B: per subtile 256 chunks, 4 slots; wave handles slot `wave`
    const bf16_t *b_src[2]; bf16_t *b_dst[2];
#pragma unroll
    for (int hh = 0; hh < 2; ++hh) {
        int c = wave * 64 + lane;
        int r = c >> 2;
        int kl = (c & 3) ^ ((r >> 1) & 3);
        b_src[hh] = w2t + ((size_t)p * D_SZ + n0 + r) * H_SZ + hh * 32 + kl * 8;
        b_dst[hh] = Bs + hh * BSUB + c * 8;
    }

    const int l16 = lane & 15, qd = lane >> 4;
    const int swz = (l16 >> 1) & 3;
    const int wr = wave >> 1, wc = wave & 1;   // 2x2 wave grid; wave tile 64x32
    int aoff[4], boff[2];
#pragma unroll
    for (int i = 0; i < 4; ++i) aoff[i] = (wr * 64 + i * 16 + l16) * 32 + ((qd ^ swz) * 8);
#pragma unroll
    for (int j = 0; j < 2; ++j) boff[j] = (wc * 32 + j * 16 + l16) * 32 + ((qd ^ swz) * 8);

    f32x4 acc[4][2];
#pragma unroll
    for (int i = 0; i < 4; ++i)
#pragma unroll
        for (int j = 0; j < 2; ++j)
            acc[i][j] = (f32x4){0.f, 0.f, 0.f, 0.f};

    for (int kt = 0; kt < H_SZ; kt += 64) {
        __syncthreads();
#pragma unroll
        for (int hh = 0; hh < 2; ++hh) {
#pragma unroll
            for (int i = 0; i < 2; ++i) glds16(a_src[hh][i] + kt, a_dst[hh][i]);
            glds16(b_src[hh] + kt, b_dst[hh]);
        }
        __syncthreads();
#pragma unroll
        for (int hh = 0; hh < 2; ++hh) {
            bf16x8 af[4], bfv[2];
#pragma unroll
            for (int i = 0; i < 4; ++i) af[i] = *(const bf16x8*)(As + hh * ASUB + aoff[i]);
#pragma unroll
            for (int j = 0; j < 2; ++j) bfv[j] = *(const bf16x8*)(Bs + hh * BSUB + boff[j]);
#pragma unroll
            for (int i = 0; i < 4; ++i)
#pragma unroll
                for (int j = 0; j < 2; ++j)
                    acc[i][j] = __builtin_amdgcn_mfma_f32_16x16x32_bf16(af[i], bfv[j], acc[i][j], 0, 0, 0);
        }
    }

    // epilogue: bias, scatter to original rows; pad rows masked
#pragma unroll
    for (int i = 0; i < 4; ++i) {
#pragma unroll
        for (int r = 0; r < 4; ++r) {
            int ml = wr * 64 + i * 16 + qd * 4 + r;
            int g = rowidx[m0 + ml];
            if (g >= 0) {
                size_t orow = (size_t)g * D_SZ;
#pragma unroll
                for (int j = 0; j < 2; ++j) {
                    int n = n0 + wc * 32 + j * 16 + l16;
                    out[orow + n] = acc[i][j][r] + b2[p * D_SZ + n];
                }
            }
        }
    }
}

// ---------------- launch ----------------

extern "C" void kernel_launch(void* const* d_in, const int* in_sizes, int n_in,
                              void* d_out, int out_size, void* d_ws, size_t ws_size,
                              hipStream_t stream) {
    const float* latents = (const float*)d_in[0];
    const float* actions = (const float*)d_in[1];
    const int*   pol     = (const int*)d_in[2];
    const float* W1      = (const float*)d_in[3];
    const float* b1      = (const float*)d_in[4];
    const float* W2      = (const float*)d_in[5];
    const float* b2      = (const float*)d_in[6];
    float* out = (float*)d_out;

    char* ws = (char*)d_ws;
    int* counts    = (int*)ws;
    int* cursors   = counts + P_SZ;
    int* blk_p     = cursors + P_SZ;
    int* blockhist = blk_p + MB_MAX;
    int* rowidx    = blockhist + NSEG * P_SZ;
    size_t pos = ((size_t)(2 * P_SZ + MB_MAX + NSEG * P_SZ + BPAD) * sizeof(int) + 255) & ~(size_t)255;
    bf16_t* hbuf= (bf16_t*)(ws + pos);  pos += (size_t)BPAD * H_SZ * 2;
    bf16_t* w1t = (bf16_t*)(ws + pos);  pos += (size_t)P_SZ * H_SZ * K1 * 2;
    bf16_t* w2t = (bf16_t*)(ws + pos);  pos += (size_t)P_SZ * D_SZ * H_SZ * 2;

    hist_block<<<NSEG, 256, 0, stream>>>(pol, blockhist, rowidx);
    prefix_kernel<<<1, 256, 0, stream>>>(blockhist, counts, cursors, blk_p);
    scatter_agg<<<NSEG, 256, 0, stream>>>(pol, cursors, rowidx);
    prep_w<<<TR1_BLOCKS + TR2_BLOCKS, 256, 0, stream>>>(W1, W2, w1t, w2t);
    gemm1_kernel<<<G1_GRID, 256, 0, stream>>>(latents, actions, rowidx, w1t, b1, blk_p, hbuf);
    gemm2_kernel<<<G2_GRID, 256, 0, stream>>>(hbuf, w2t, b2, blk_p, rowidx, out);
}

// Round 13
// 192.628 us; speedup vs baseline: 1.6100x; 1.0925x over previous
//
#include <hip/hip_runtime.h>
#include <hip/hip_bf16.h>
#include <stdint.h>

#define B_SZ 16384
#define P_SZ 8
#define D_SZ 512
#define A_SZ 64
#define K1 576    // D + A
#define H_SZ 1024
#define NSEG 64
#define MB_MAX 72               // max 256-row m-blocks after per-policy padding
#define BPAD (B_SZ + P_SZ*256)  // 18432 padded sorted-row capacity
#define PREP_BLOCKS (BPAD * 72 / 256)   // 5184
#define TR1_BLOCKS (P_SZ * 9 * 16)      // 1152  (576/64 x 1024/64)
#define TR2_BLOCKS (P_SZ * 16 * 8)      // 1024  (1024/64 x 512/64)
#define G1_GRID (BPAD / 128 * (H_SZ / 128))   // 1152
#define G2_GRID (BPAD / 128 * (D_SZ / 64))    // 1152

typedef __bf16 bf16_t;
typedef __bf16 bf16x8 __attribute__((ext_vector_type(8)));
typedef float f32x4 __attribute__((ext_vector_type(4)));

__device__ __forceinline__ void glds16(const void* g, void* l) {
    __builtin_amdgcn_global_load_lds(
        (const __attribute__((address_space(1))) unsigned*)g,
        (__attribute__((address_space(3))) unsigned*)l, 16, 0, 0);
}

// ---------------- sort prep ----------------

__global__ __launch_bounds__(256) void hist_block(const int* __restrict__ pol,
                                                  int* __restrict__ blockhist,
                                                  int* __restrict__ rowidx) {
    __shared__ int lc[P_SZ];
    int t = threadIdx.x;
    if (t < P_SZ) lc[t] = 0;
    __syncthreads();
    int gid = blockIdx.x * 256 + t;
    rowidx[gid] = -1;
    if (gid < BPAD - B_SZ) rowidx[B_SZ + gid] = -1;
    atomicAdd(&lc[pol[gid]], 1);
    __syncthreads();
    if (t < P_SZ) blockhist[blockIdx.x * P_SZ + t] = lc[t];
}

// parallel reduction (was: 64 serial dependent global reads on one thread)
__global__ __launch_bounds__(256) void prefix_kernel(const int* __restrict__ blockhist,
                                                     int* __restrict__ counts,
                                                     int* __restrict__ cursors,
                                                     int* __restrict__ blk_p) {
    __shared__ int csh[P_SZ];
    int t = threadIdx.x;
    int p = t >> 5, i = t & 31;          // 8 policies x 32 lanes
    int s = blockhist[i * P_SZ + p] + blockhist[(i + 32) * P_SZ + p];
#pragma unroll
    for (int m = 16; m >= 1; m >>= 1) s += __shfl_xor(s, m, 32);
    if (i == 0) csh[p] = s;
    __syncthreads();
    if (t == 0) {
        int run = 0;
        for (int pp = 0; pp < P_SZ; ++pp) {
            counts[pp] = csh[pp];
            cursors[pp] = run;
            run += ((csh[pp] + 255) >> 8) * 256;
        }
    }
    if (t < MB_MAX) {
        int run = 0, val = -1;
#pragma unroll
        for (int pp = 0; pp < P_SZ; ++pp) {
            int nb = (csh[pp] + 255) >> 8;
            if (t >= run && t < run + nb) val = pp;
            run += nb;
        }
        blk_p[t] = val;
    }
}

__global__ __launch_bounds__(256) void scatter_agg(const int* __restrict__ pol,
                                                   int* __restrict__ cursors,
                                                   int* __restrict__ rowidx) {
    __shared__ int lc[P_SZ], base_s[P_SZ];
    int t = threadIdx.x;
    if (t < P_SZ) lc[t] = 0;
    __syncthreads();
    int i = blockIdx.x * 256 + t;
    int p = pol[i];
    int lpos = atomicAdd(&lc[p], 1);
    __syncthreads();
    if (t < P_SZ) base_s[t] = atomicAdd(&cursors[t], lc[t]);
    __syncthreads();
    rowidx[base_s[p] + lpos] = i;
}

// ---------------- prep_all: fused x-gather/convert + weight transposes ----------------
// Transpose path: exact grid (no dead blocks), 64x64 f32 tiles, packed bf16x8 stores.

__global__ __launch_bounds__(256) void prep_all(const float* __restrict__ latents,
                                                const float* __restrict__ actions,
                                                const int* __restrict__ rowidx,
                                                const float* __restrict__ W1,
                                                const float* __restrict__ W2,
                                                bf16_t* __restrict__ xs,
                                                bf16_t* __restrict__ w1t,
                                                bf16_t* __restrict__ w2t) {
    int bx = blockIdx.x;
    int tid = threadIdx.x;
    if (bx < PREP_BLOCKS) {
        int idx = bx * 256 + tid;
        int s = idx / 72;
        int col = (idx - s * 72) * 8;
        int g = rowidx[s];
        bf16x8 o;
        if (g < 0) {
            o = (bf16x8){0,0,0,0,0,0,0,0};
        } else {
            const float* src;
            if (col < D_SZ) src = latents + (size_t)g * D_SZ + col;
            else            src = actions + (size_t)g * A_SZ + (col - D_SZ);
            f32x4 v0 = *(const f32x4*)src;
            f32x4 v1 = *(const f32x4*)(src + 4);
            o[0] = (bf16_t)v0[0]; o[1] = (bf16_t)v0[1]; o[2] = (bf16_t)v0[2]; o[3] = (bf16_t)v0[3];
            o[4] = (bf16_t)v1[0]; o[5] = (bf16_t)v1[1]; o[6] = (bf16_t)v1[2]; o[7] = (bf16_t)v1[3];
        }
        *(bf16x8*)(xs + (size_t)s * K1 + col) = o;
        return;
    }
    int tz = bx - PREP_BLOCKS;
    const float* Wp; bf16_t* WTp; int K, N, k0, n0;
    if (tz < TR1_BLOCKS) {
        int p = tz / 144, rem = tz % 144;    // 9 k-tiles x 16 n-tiles
        k0 = (rem / 16) * 64; n0 = (rem % 16) * 64;
        K = K1; N = H_SZ;
        Wp = W1 + (size_t)p * K1 * H_SZ;
        WTp = w1t + (size_t)p * H_SZ * K1;
    } else {
        int u = tz - TR1_BLOCKS;
        int p = u / 128, rem = u % 128;      // 16 k-tiles x 8 n-tiles
        k0 = (rem / 8) * 64; n0 = (rem % 8) * 64;
        K = H_SZ; N = D_SZ;
        Wp = W2 + (size_t)p * H_SZ * D_SZ;
        WTp = w2t + (size_t)p * D_SZ * H_SZ;
    }
    __shared__ float ls[64][65];
#pragma unroll
    for (int e = 0; e < 4; ++e) {
        int idx = e * 256 + tid;
        int kk = idx >> 4, nn = (idx & 15) * 4;
        f32x4 v = *(const f32x4*)&Wp[(size_t)(k0 + kk) * N + n0 + nn];
        ls[kk][nn]     = v[0];
        ls[kk][nn + 1] = v[1];
        ls[kk][nn + 2] = v[2];
        ls[kk][nn + 3] = v[3];
    }
    __syncthreads();
#pragma unroll
    for (int e = 0; e < 2; ++e) {
        int idx = e * 256 + tid;
        int nn = idx >> 3, ks = (idx & 7) * 8;
        bf16x8 o;
#pragma unroll
        for (int q = 0; q < 8; ++q) o[q] = (bf16_t)ls[ks + q][nn];
        *(bf16x8*)&WTp[(size_t)(n0 + nn) * K + k0 + ks] = o;
    }
}

// ---------------- GEMMs: BM=128, 2x2 wave grid, XCD-local n-sweep, BK=64 -----------
// SESSION OPTIMUM (measured 192.6us in round 5). Structural floor for this
// compiler: 2-barrier glds16 loop, ~40us/GEMM, invariant across 7 configs
// (tile/occupancy/pipelining/reg-direct/fusion all falsified, rounds 0-12).
// XCD-local 1D swizzle (T1): wid=(b&7)*144+(b>>3), n fastest per XCD -> A-tile
// L2-resident across its n-blocks (FETCH 59->25MB measured). Chunk-XOR swizzle:
// stored pos (c&3) holds logical (c&3)^((r>>1)&3) -> 0 bank conflicts (measured).

__global__ __launch_bounds__(256, 3) void gemm1_kernel(
    const bf16_t* __restrict__ xs, const bf16_t* __restrict__ w1t,
    const float* __restrict__ b1, const int* __restrict__ blk_p,
    bf16_t* __restrict__ h) {

    const int b = blockIdx.x;
    const int wid = (b & 7) * (G1_GRID / 8) + (b >> 3);   // XCD-contiguous work id
    const int mb = wid >> 3;
    const int nb = wid & 7;
    const int p = blk_p[mb >> 1];
    if (p < 0) return;
    const int m0 = mb * 128;
    const int n0 = nb * 128;

    constexpr int SUB = 128 * 32;                    // elems per 32-k subtile
    __shared__ __align__(16) bf16_t As[2 * SUB];     // 16 KB
    __shared__ __align__(16) bf16_t Bs[2 * SUB];     // 16 KB

    const int tid = threadIdx.x;
    const int wave = tid >> 6, lane = tid & 63;

    // per subtile hh: A/B each 512 chunks, 8 slots of 64; wave handles slots wave*2+i
    const bf16_t *a_src[2][2], *b_src[2][2];
    bf16_t *a_dst[2][2], *b_dst[2][2];
#pragma unroll
    for (int hh = 0; hh < 2; ++hh)
#pragma unroll
        for (int i = 0; i < 2; ++i) {
            int c = (wave * 2 + i) * 64 + lane;
            int r = c >> 2;
            int kl = (c & 3) ^ ((r >> 1) & 3);
            a_src[hh][i] = xs + (size_t)(m0 + r) * K1 + hh * 32 + kl * 8;
            a_dst[hh][i] = As + hh * SUB + c * 8;
            b_src[hh][i] = w1t + ((size_t)p * H_SZ + n0 + r) * K1 + hh * 32 + kl * 8;
            b_dst[hh][i] = Bs + hh * SUB + c * 8;
        }

    const int l16 = lane & 15, qd = lane >> 4;
    const int swz = (l16 >> 1) & 3;
    const int wr = wave >> 1, wc = wave & 1;   // 2x2 wave grid; wave tile 64x64
    int aoff[4], boff[4];
#pragma unroll
    for (int i = 0; i < 4; ++i) aoff[i] = (wr * 64 + i * 16 + l16) * 32 + ((qd ^ swz) * 8);
#pragma unroll
    for (int j = 0; j < 4; ++j) boff[j] = (wc * 64 + j * 16 + l16) * 32 + ((qd ^ swz) * 8);

    f32x4 acc[4][4];
#pragma unroll
    for (int i = 0; i < 4; ++i)
#pragma unroll
        for (int j = 0; j < 4; ++j)
            acc[i][j] = (f32x4){0.f, 0.f, 0.f, 0.f};

    for (int kt = 0; kt < K1; kt += 64) {
        __syncthreads();   // previous iter's frags consumed
#pragma unroll
        for (int hh = 0; hh < 2; ++hh)
#pragma unroll
            for (int i = 0; i < 2; ++i) {
                glds16(a_src[hh][i] + kt, a_dst[hh][i]);
                glds16(b_src[hh][i] + kt, b_dst[hh][i]);
            }
        __syncthreads();   // staging complete (compiler inserts vmcnt(0))
#pragma unroll
        for (int hh = 0; hh < 2; ++hh) {
            bf16x8 af[4], bfv[4];
#pragma unroll
            for (int i = 0; i < 4; ++i) af[i] = *(const bf16x8*)(As + hh * SUB + aoff[i]);
#pragma unroll
            for (int j = 0; j < 4; ++j) bfv[j] = *(const bf16x8*)(Bs + hh * SUB + boff[j]);
#pragma unroll
            for (int i = 0; i < 4; ++i)
#pragma unroll
                for (int j = 0; j < 4; ++j)
                    acc[i][j] = __builtin_amdgcn_mfma_f32_16x16x32_bf16(af[i], bfv[j], acc[i][j], 0, 0, 0);
        }
    }

    // epilogue: bias + relu -> h (padded sorted layout)
#pragma unroll
    for (int i = 0; i < 4; ++i) {
#pragma unroll
        for (int r = 0; r < 4; ++r) {
            int ml = wr * 64 + i * 16 + qd * 4 + r;     // C/D: row = quad*4 + reg
            size_t row = (size_t)(m0 + ml);
#pragma unroll
            for (int j = 0; j < 4; ++j) {
                int n = n0 + wc * 64 + j * 16 + l16;    // C/D: col = lane&15
                float v = acc[i][j][r] + b1[p * H_SZ + n];
                h[row * H_SZ + n] = (bf16_t)fmaxf(v, 0.f);
            }
        }
    }
}

__global__ __launch_bounds__(256, 4) void gemm2_kernel(
    const bf16_t* __restrict__ h, const bf16_t* __restrict__ w2t,
    const float* __restrict__ b2, const int* __restrict__ blk_p,
    const int* __restrict__ rowidx, float* __restrict__ out) {

    const int b = blockIdx.x;
    const int wid = (b & 7) * (G2_GRID / 8) + (b >> 3);   // XCD-contiguous work id
    const int mb = wid >> 3;
    const int nb = wid & 7;
    const int p = blk_p[mb >> 1];
    if (p < 0) return;
    const int m0 = mb * 128;
    const int n0 = nb * 64;

    constexpr int ASUB = 128 * 32;                   // A subtile elems
    constexpr int BSUB = 64 * 32;                    // B subtile elems
    __shared__ __align__(16) bf16_t As[2 * ASUB];    // 16 KB
    __shared__ __align__(16) bf16_t Bs[2 * BSUB];    // 8 KB

    const int tid = threadIdx.x;
    const int wave = tid >> 6, lane = tid & 63;

    // A: per subtile 512 chunks, 8 slots; wave handles slots wave*2+i
    const bf16_t *a_src[2][2]; bf16_t *a_dst[2][2];
#pragma unroll
    for (int hh = 0; hh < 2; ++hh)
#pragma unroll
        for (int i = 0; i < 2; ++i) {
            int c = (wave * 2 + i) * 64 + lane;
            int r = c >> 2;
            int kl = (c & 3) ^ ((r >> 1) & 3);
            a_src[hh][i] = h + (size_t)(m0 + r) * H_SZ + hh * 32 + kl * 8;
            a_dst[hh][i] = As + hh * ASUB + c * 8;
        }
    // B: per subtile 256 chunks, 4 slots; wave handles slot `wave`
    const bf16_t *b_src[2]; bf16_t *b_dst[2];
#pragma unroll
    for (int hh = 0; hh < 2; ++hh) {
        int c = wave * 64 + lane;
        int r = c >> 2;
        int kl = (c & 3) ^ ((r >> 1) & 3);
        b_src[hh] = w2t + ((size_t)p * D_SZ + n0 + r) * H_SZ + hh * 32 + kl * 8;
        b_dst[hh] = Bs + hh * BSUB + c * 8;
    }

    const int l16 = lane & 15, qd = lane >> 4;
    const int swz = (l16 >> 1) & 3;
    const int wr = wave >> 1, wc = wave & 1;   // 2x2 wave grid; wave tile 64x32
    int aoff[4], boff[2];
#pragma unroll
    for (int i = 0; i < 4; ++i) aoff[i] = (wr * 64 + i * 16 + l16) * 32 + ((qd ^ swz) * 8);
#pragma unroll
    for (int j = 0; j < 2; ++j) boff[j] = (wc * 32 + j * 16 + l16) * 32 + ((qd ^ swz) * 8);

    f32x4 acc[4][2];
#pragma unroll
    for (int i = 0; i < 4; ++i)
#pragma unroll
        for (int j = 0; j < 2; ++j)
            acc[i][j] = (f32x4){0.f, 0.f, 0.f, 0.f};

    for (int kt = 0; kt < H_SZ; kt += 64) {
        __syncthreads();
#pragma unroll
        for (int hh = 0; hh < 2; ++hh) {
#pragma unroll
            for (int i = 0; i < 2; ++i) glds16(a_src[hh][i] + kt, a_dst[hh][i]);
            glds16(b_src[hh] + kt, b_dst[hh]);
        }
        __syncthreads();
#pragma unroll
        for (int hh = 0; hh < 2; ++hh) {
            bf16x8 af[4], bfv[2];
#pragma unroll
            for (int i = 0; i < 4; ++i) af[i] = *(const bf16x8*)(As + hh * ASUB + aoff[i]);
#pragma unroll
            for (int j = 0; j < 2; ++j) bfv[j] = *(const bf16x8*)(Bs + hh * BSUB + boff[j]);
#pragma unroll
            for (int i = 0; i < 4; ++i)
#pragma unroll
                for (int j = 0; j < 2; ++j)
                    acc[i][j] = __builtin_amdgcn_mfma_f32_16x16x32_bf16(af[i], bfv[j], acc[i][j], 0, 0, 0);
        }
    }

    // epilogue: bias, scatter to original rows; pad rows masked
#pragma unroll
    for (int i = 0; i < 4; ++i) {
#pragma unroll
        for (int r = 0; r < 4; ++r) {
            int ml = wr * 64 + i * 16 + qd * 4 + r;
            int g = rowidx[m0 + ml];
            if (g >= 0) {
                size_t orow = (size_t)g * D_SZ;
#pragma unroll
                for (int j = 0; j < 2; ++j) {
                    int n = n0 + wc * 32 + j * 16 + l16;
                    out[orow + n] = acc[i][j][r] + b2[p * D_SZ + n];
                }
            }
        }
    }
}

// ---------------- launch ----------------

extern "C" void kernel_launch(void* const* d_in, const int* in_sizes, int n_in,
                              void* d_out, int out_size, void* d_ws, size_t ws_size,
                              hipStream_t stream) {
    const float* latents = (const float*)d_in[0];
    const float* actions = (const float*)d_in[1];
    const int*   pol     = (const int*)d_in[2];
    const float* W1      = (const float*)d_in[3];
    const float* b1      = (const float*)d_in[4];
    const float* W2      = (const float*)d_in[5];
    const float* b2      = (const float*)d_in[6];
    float* out = (float*)d_out;

    char* ws = (char*)d_ws;
    int* counts    = (int*)ws;
    int* cursors   = counts + P_SZ;
    int* blk_p     = cursors + P_SZ;
    int* blockhist = blk_p + MB_MAX;
    int* rowidx    = blockhist + NSEG * P_SZ;
    size_t pos = ((size_t)(2 * P_SZ + MB_MAX + NSEG * P_SZ + BPAD) * sizeof(int) + 255) & ~(size_t)255;
    bf16_t* xs  = (bf16_t*)(ws + pos);  pos += (size_t)BPAD * K1 * 2;
    bf16_t* hbuf= (bf16_t*)(ws + pos);  pos += (size_t)BPAD * H_SZ * 2;
    bf16_t* w1t = (bf16_t*)(ws + pos);  pos += (size_t)P_SZ * H_SZ * K1 * 2;
    bf16_t* w2t = (bf16_t*)(ws + pos);  pos += (size_t)P_SZ * D_SZ * H_SZ * 2;

    hist_block<<<NSEG, 256, 0, stream>>>(pol, blockhist, rowidx);
    prefix_kernel<<<1, 256, 0, stream>>>(blockhist, counts, cursors, blk_p);
    scatter_agg<<<NSEG, 256, 0, stream>>>(pol, cursors, rowidx);
    prep_all<<<PREP_BLOCKS + TR1_BLOCKS + TR2_BLOCKS, 256, 0, stream>>>(
        latents, actions, rowidx, W1, W2, xs, w1t, w2t);
    gemm1_kernel<<<G1_GRID, 256, 0, stream>>>(xs, w1t, b1, blk_p, hbuf);
    gemm2_kernel<<<G2_GRID, 256, 0, stream>>>(hbuf, w2t, b2, blk_p, rowidx, out);
}